// Round 1
// baseline (536.109 us; speedup 1.0000x reference)
//
#include <hip/hip_runtime.h>
#include <stdint.h>

// Problem dims
#define B_  32
#define T_  512
#define DE_ 512
#define H_  640
#define V_  4096
#define J_  640

typedef __attribute__((ext_vector_type(4))) float  f32x4;
typedef __attribute__((ext_vector_type(8))) __bf16 bf16x8;

typedef __attribute__((address_space(3))) void LdsV;
typedef __attribute__((address_space(1))) void GloV;

__device__ __forceinline__ unsigned short f2bf(float f) {
    uint32_t u = __builtin_bit_cast(uint32_t, f);
    u += 0x7fffu + ((u >> 16) & 1u);   // round-to-nearest-even
    return (unsigned short)(u >> 16);
}

// ---------------- fp32 -> bf16 elementwise convert ----------------
__global__ void conv_f32_bf16_k(const float* __restrict__ src,
                                unsigned short* __restrict__ dst, int n) {
    int i = blockIdx.x * blockDim.x + threadIdx.x;
    if (i < n) dst[i] = f2bf(src[i]);
}

// ---------------- encoder (B,D,T) -> bf16 (B*T, D) transpose ----------------
__global__ void enc_transpose_k(const float* __restrict__ enc,
                                unsigned short* __restrict__ out) {
    __shared__ float tile[32][33];
    int b  = blockIdx.z;
    int t0 = blockIdx.x * 32, d0 = blockIdx.y * 32;
    int tx = threadIdx.x & 31;
    int ty = (threadIdx.x >> 5) * 4;
    const float* src = enc + ((size_t)b * DE_ + d0) * T_ + t0;
#pragma unroll
    for (int i = 0; i < 4; i++)
        tile[ty + i][tx] = src[(size_t)(ty + i) * T_ + tx];  // coalesced over t
    __syncthreads();
    unsigned short* dst = out + ((size_t)b * T_ + t0) * DE_ + d0;
#pragma unroll
    for (int i = 0; i < 4; i++)
        dst[(size_t)(ty + i) * DE_ + tx] = f2bf(tile[tx][ty + i]);  // coalesced over d
}

// ---------------- LSTM gates: gates[b][n] = x_b . wih[n] + h_b . whh[n] + biases ----------------
// grid = 4*H_ blocks (one gate row each), 64 threads (one wave)
__global__ void lstm_gates_k(const float* __restrict__ x, const int* __restrict__ tok,
                             const float* __restrict__ emb, const float* __restrict__ h,
                             const float* __restrict__ wih, const float* __restrict__ whh,
                             const float* __restrict__ bih, const float* __restrict__ bhh,
                             float* __restrict__ gates) {
    int n = blockIdx.x, lane = threadIdx.x;
    float wi[10], wh[10];
#pragma unroll
    for (int i = 0; i < 10; i++) {
        wi[i] = wih[(size_t)n * H_ + lane + 64 * i];   // coalesced
        wh[i] = whh[(size_t)n * H_ + lane + 64 * i];
    }
    float bias = bih[n] + bhh[n];
    for (int b = 0; b < B_; b++) {
        const float* xr = tok ? (emb + (size_t)tok[b] * H_) : (x + (size_t)b * H_);
        const float* hr = h + (size_t)b * H_;
        float s = 0.f;
#pragma unroll
        for (int i = 0; i < 10; i++)
            s += wi[i] * xr[lane + 64 * i] + wh[i] * hr[lane + 64 * i];
#pragma unroll
        for (int off = 32; off > 0; off >>= 1)
            s += __shfl_down(s, off, 64);
        if (lane == 0) gates[(size_t)b * (4 * H_) + n] = s + bias;
    }
}

// ---------------- LSTM pointwise update (+ optional target_length passthrough) ----------------
__global__ void lstm_update_k(const float* __restrict__ gates, const float* __restrict__ c_in,
                              float* __restrict__ h_out, float* __restrict__ c_out,
                              const int* __restrict__ tlen, float* __restrict__ tlen_out) {
    int idx = blockIdx.x * blockDim.x + threadIdx.x;
    if (tlen_out != nullptr && idx < B_) tlen_out[idx] = (float)tlen[idx];
    if (idx >= B_ * H_) return;
    int b = idx / H_, j = idx - b * H_;
    const float* gr = gates + (size_t)b * 4 * H_;
    float ig = 1.f / (1.f + expf(-gr[j]));
    float fg = 1.f / (1.f + expf(-gr[H_ + j]));
    float gg = tanhf(gr[2 * H_ + j]);
    float og = 1.f / (1.f + expf(-gr[3 * H_ + j]));
    float c  = fg * c_in[idx] + ig * gg;
    h_out[idx] = og * tanhf(c);
    c_out[idx] = c;
}

// ---------------- g[b][j] = h1_b . wpred[j] + bpred[j] ----------------
__global__ void pred_g_k(const float* __restrict__ h1, const float* __restrict__ wp,
                         const float* __restrict__ bp, float* __restrict__ g) {
    int j = blockIdx.x, lane = threadIdx.x;
    float w[10];
#pragma unroll
    for (int i = 0; i < 10; i++) w[i] = wp[(size_t)j * H_ + lane + 64 * i];
    for (int b = 0; b < B_; b++) {
        const float* hr = h1 + (size_t)b * H_;
        float s = 0.f;
#pragma unroll
        for (int i = 0; i < 10; i++) s += w[i] * hr[lane + 64 * i];
#pragma unroll
        for (int off = 32; off > 0; off >>= 1)
            s += __shfl_down(s, off, 64);
        if (lane == 0) g[(size_t)b * J_ + j] = s + bp[j];
    }
}

// ---------------- m97-style bf16 MFMA GEMM, C = A (MxK) * B^T (NxK) ----------------
// 128x128 tile, BK=32, 4 waves/block, global_load_lds width 16.
// EPI==0: outF[m*ldn+n] = acc + bias[n]
// EPI==1: outU[m*ldn+n] = bf16(relu(acc + bias[n] + g[(m>>9)*J_ + n]))
template <int K, int EPI>
__global__ __launch_bounds__(256) void gemm_bt_k(
        const unsigned short* __restrict__ A, const unsigned short* __restrict__ Bm,
        const float* __restrict__ bias, const float* __restrict__ g,
        float* __restrict__ outF, unsigned short* __restrict__ outU, int ldn) {
    __shared__ __align__(16) unsigned short As[128 * 32];
    __shared__ __align__(16) unsigned short Bs[128 * 32];
    const int tid  = threadIdx.x;
    const int w    = tid >> 6;          // wave 0..3
    const int lane = tid & 63;
    const int tile_n = blockIdx.x * 128;
    const int tile_m = blockIdx.y * 128;
    const int wm = w & 1, wn = w >> 1;  // wave -> 64x64 quadrant
    const int l15 = lane & 15, quad = lane >> 4;
    const int lr = lane >> 2, lc = lane & 3;  // staging: row-in-chunk, 16B slot

    f32x4 zero = {0.f, 0.f, 0.f, 0.f};
    f32x4 acc[4][4];
#pragma unroll
    for (int i = 0; i < 4; i++)
#pragma unroll
        for (int j = 0; j < 4; j++) acc[i][j] = zero;

    for (int k0 = 0; k0 < K; k0 += 32) {
        // stage A and B tiles: each wave fills 2 chunks of 1 KiB each per matrix
#pragma unroll
        for (int cc = 0; cc < 2; cc++) {
            const int c = 2 * w + cc;
            const char* ga = (const char*)(A + (size_t)(tile_m + 16 * c + lr) * K)
                             + (size_t)k0 * 2 + lc * 16;
            __builtin_amdgcn_global_load_lds((const GloV*)ga,
                    (LdsV*)((char*)As + c * 1024), 16, 0, 0);
            const char* gb = (const char*)(Bm + (size_t)(tile_n + 16 * c + lr) * K)
                             + (size_t)k0 * 2 + lc * 16;
            __builtin_amdgcn_global_load_lds((const GloV*)gb,
                    (LdsV*)((char*)Bs + c * 1024), 16, 0, 0);
        }
        __syncthreads();   // drains vmcnt then barrier

        bf16x8 av[4], bv[4];
#pragma unroll
        for (int i = 0; i < 4; i++) {
            av[i] = *(const bf16x8*)&As[(wm * 64 + i * 16 + l15) * 32 + quad * 8];
            bv[i] = *(const bf16x8*)&Bs[(wn * 64 + i * 16 + l15) * 32 + quad * 8];
        }
#pragma unroll
        for (int i = 0; i < 4; i++)
#pragma unroll
            for (int j = 0; j < 4; j++)
                acc[i][j] = __builtin_amdgcn_mfma_f32_16x16x32_bf16(av[i], bv[j], acc[i][j], 0, 0, 0);
        __syncthreads();   // protect LDS from next iteration's staging
    }

    // epilogue: C/D layout col=lane&15, row=quad*4+reg (verified m89)
#pragma unroll
    for (int i = 0; i < 4; i++) {
        const int mb = tile_m + wm * 64 + i * 16 + quad * 4;
#pragma unroll
        for (int j = 0; j < 4; j++) {
            const int n = tile_n + wn * 64 + j * 16 + l15;
#pragma unroll
            for (int r = 0; r < 4; r++) {
                float v = acc[i][j][r] + bias[n];
                if (EPI == 0) {
                    outF[(size_t)(mb + r) * ldn + n] = v;
                } else {
                    v += g[(size_t)((mb + r) >> 9) * J_ + n];
                    outU[(size_t)(mb + r) * ldn + n] = f2bf(fmaxf(v, 0.f));
                }
            }
        }
    }
}

extern "C" void kernel_launch(void* const* d_in, const int* in_sizes, int n_in,
                              void* d_out, int out_size, void* d_ws, size_t ws_size,
                              hipStream_t stream) {
    const float* enc   = (const float*)d_in[0];
    const int*   tgt   = (const int*)d_in[1];
    const int*   tlen  = (const int*)d_in[2];
    const float* st1   = (const float*)d_in[3];   // (2,B,H) h states
    const float* st2   = (const float*)d_in[4];   // (2,B,H) c states
    const float* wih0  = (const float*)d_in[5];
    const float* whh0  = (const float*)d_in[6];
    const float* bih0  = (const float*)d_in[7];
    const float* bhh0  = (const float*)d_in[8];
    const float* wih1  = (const float*)d_in[9];
    const float* whh1  = (const float*)d_in[10];
    const float* bih1  = (const float*)d_in[11];
    const float* bhh1  = (const float*)d_in[12];
    const float* emb   = (const float*)d_in[13];
    const float* wenc  = (const float*)d_in[14];
    const float* benc  = (const float*)d_in[15];
    const float* wpred = (const float*)d_in[16];
    const float* bpred = (const float*)d_in[17];
    const float* wout  = (const float*)d_in[18];
    const float* bout  = (const float*)d_in[19];

    float* out      = (float*)d_out;
    float* out_tlen = out + (size_t)B_ * T_ * V_;
    float* h0 = out_tlen + B_;            // output_states_1[0]
    float* h1 = h0 + B_ * H_;             // output_states_1[1]
    float* c0 = h1 + B_ * H_;             // output_states_2[0]
    float* c1 = c0 + B_ * H_;             // output_states_2[1]

    // workspace layout (~44.1 MB)
    unsigned short* encB  = (unsigned short*)d_ws;                 // 16384*512 bf16
    unsigned short* pB    = encB + (size_t)B_ * T_ * DE_;          // 16384*640 bf16
    unsigned short* woutB = pB + (size_t)B_ * T_ * J_;             // 4096*640 bf16
    unsigned short* wencB = woutB + (size_t)V_ * J_;               // 640*512 bf16
    float* gates = (float*)(wencB + (size_t)J_ * DE_);             // 32*2560 f32
    float* gvec  = gates + B_ * 4 * H_;                            // 32*640 f32

    // weight converts + encoder transpose (independent)
    conv_f32_bf16_k<<<(V_ * J_ + 255) / 256, 256, 0, stream>>>(wout, woutB, V_ * J_);
    conv_f32_bf16_k<<<(J_ * DE_ + 255) / 256, 256, 0, stream>>>(wenc, wencB, J_ * DE_);
    enc_transpose_k<<<dim3(T_ / 32, DE_ / 32, B_), 256, 0, stream>>>(enc, encB);

    // LSTM layer 0 (x = embed[targets])
    lstm_gates_k<<<4 * H_, 64, 0, stream>>>(nullptr, tgt, emb, st1, wih0, whh0, bih0, bhh0, gates);
    lstm_update_k<<<(B_ * H_ + 255) / 256, 256, 0, stream>>>(gates, st2, h0, c0, tlen, out_tlen);
    // LSTM layer 1 (x = h0)
    lstm_gates_k<<<4 * H_, 64, 0, stream>>>(h0, nullptr, nullptr, st1 + B_ * H_, wih1, whh1, bih1, bhh1, gates);
    lstm_update_k<<<(B_ * H_ + 255) / 256, 256, 0, stream>>>(gates, st2 + B_ * H_, h1, c1, nullptr, nullptr);
    // g = h1 @ W_pred^T + b_pred
    pred_g_k<<<J_, 64, 0, stream>>>(h1, wpred, bpred, gvec);

    // P = bf16(relu(enc @ W_enc^T + b_enc + g))   [M=16384, N=640, K=512]
    gemm_bt_k<DE_, 1><<<dim3(J_ / 128, (B_ * T_) / 128), 256, 0, stream>>>(
        encB, wencB, benc, gvec, nullptr, pB, J_);
    // out = P @ W_out^T + b_out                   [M=16384, N=4096, K=640]
    gemm_bt_k<J_, 0><<<dim3(V_ / 128, (B_ * T_) / 128), 256, 0, stream>>>(
        pB, woutB, bout, nullptr, out, nullptr, V_);
}